// Round 5
// baseline (355.562 us; speedup 1.0000x reference)
//
#include <hip/hip_runtime.h>

#define NB 4
#define LQ 512
#define LK 512
#define EE 128
#define DD 256

// ===== ATTRIBUTION ROUND: each kernel body repeats REP_* times (idempotent) =====
// Purpose: push each dispatch above the ~41us fillBuffer threshold so all three
// kernels surface in rocprof top-5 with their own counters. per-kernel dur =
// instance_dur / REP. Kernels are otherwise byte-identical to the R2 baseline.
#define REP_K1 5
#define REP_K2 6
#define REP_K3 10

__device__ __forceinline__ float fast_rcp(float x) { return __builtin_amdgcn_rcpf(x); }

// K1: rows 0..2047 = query@Wc1 -> EqT[b][e][q] = exp(2q) TRANSPOSED;
//     rows 2048..4095 = key@Wc2 -> Ek[b][l][e] = exp(2k) row-major.
__global__ __launch_bounds__(256) void proj_exp_kernel(
    const float* __restrict__ query, const float* __restrict__ key,
    const float* __restrict__ Wc1, const float* __restrict__ Wc2,
    float* __restrict__ EqT, float* __restrict__ Ek)
{
    __shared__ float in_s[8][DD];   // 8 KB
    const int r0 = blockIdx.x * 8;
    const bool is_q = (r0 < NB * LQ);
    const float* src = is_q ? query : key;
    const float* W   = is_q ? Wc1   : Wc2;
    const int rbase  = is_q ? r0    : r0 - NB * LQ;

    #pragma unroll 1
    for (int rep = 0; rep < REP_K1; ++rep) {
        __syncthreads();
        const float4* srow4 = (const float4*)(src + (size_t)rbase * DD);
        #pragma unroll
        for (int i = 0; i < 2; ++i)
            ((float4*)in_s)[i * 256 + threadIdx.x] = srow4[i * 256 + threadIdx.x];
        __syncthreads();

        const int c  = threadIdx.x & 127;
        const int rg = threadIdx.x >> 7;   // 0..1 (wave-uniform)
        float acc[4] = {0.f, 0.f, 0.f, 0.f};
        for (int d = 0; d < DD; d += 8) {
            const float w0 = W[(d + 0) * EE + c];
            const float w1 = W[(d + 1) * EE + c];
            const float w2 = W[(d + 2) * EE + c];
            const float w3 = W[(d + 3) * EE + c];
            const float w4 = W[(d + 4) * EE + c];
            const float w5 = W[(d + 5) * EE + c];
            const float w6 = W[(d + 6) * EE + c];
            const float w7 = W[(d + 7) * EE + c];
            #pragma unroll
            for (int i = 0; i < 4; ++i) {
                const float4 xa = *(const float4*)&in_s[rg * 4 + i][d];
                const float4 xb = *(const float4*)&in_s[rg * 4 + i][d + 4];
                acc[i] += xa.x * w0 + xa.y * w1 + xa.z * w2 + xa.w * w3
                        + xb.x * w4 + xb.y * w5 + xb.z * w6 + xb.w * w7;
            }
        }
        if (is_q) {
            const int b    = rbase >> 9;
            const int qloc = (rbase & 511) + rg * 4;
            float4 o;
            o.x = __expf(2.0f * acc[0]); o.y = __expf(2.0f * acc[1]);
            o.z = __expf(2.0f * acc[2]); o.w = __expf(2.0f * acc[3]);
            *(float4*)&EqT[((size_t)(b * EE + c)) * LQ + qloc] = o;
        } else {
            #pragma unroll
            for (int i = 0; i < 4; ++i)
                Ek[(size_t)(rbase + rg * 4 + i) * EE + c] = __expf(2.0f * acc[i]);
        }
        asm volatile("" ::: "memory");   // keep reps live
    }
}

// K2: block = (b, 4 l-rows), 512 threads. (R1-fused-tail variant, = R2 bench)
__global__ __launch_bounds__(512) void atten_kernel(
    const float* __restrict__ EqT, const float* __restrict__ Ek,
    const float* __restrict__ vc, float* __restrict__ attn)
{
    __shared__ float  ek_s[4][EE];      // 2 KB
    __shared__ float  vc_s[EE];         // 0.5 KB
    __shared__ float  s2p_s[4][4][LQ];  // 32 KB
    __shared__ float  sj_s[4][LQ];      // 8 KB
    __shared__ float2 mZ_s[4][2];
    __shared__ float  scale_s[4][2];
    const int b   = blockIdx.x >> 7;
    const int lt  = blockIdx.x & 127;
    const int l0  = lt * 4;
    const int tid = threadIdx.x;
    const int qq  = tid & 127;
    const int eg  = tid >> 7;

    #pragma unroll 1
    for (int rep = 0; rep < REP_K2; ++rep) {
        __syncthreads();
        ((float*)ek_s)[tid] = Ek[((size_t)b * LK + l0) * EE + tid];
        if (tid < EE) vc_s[tid] = vc[tid];
        __syncthreads();

        float vcsum = 0.f;
        #pragma unroll
        for (int e = 0; e < EE; e += 4) {
            const float4 v = *(const float4*)&vc_s[e];
            vcsum += (v.x + v.y) + (v.z + v.w);
        }

        const float4* eq4 = (const float4*)(EqT + (size_t)b * EE * LQ);
        float s2[4][4];
        #pragma unroll
        for (int l = 0; l < 4; ++l) { s2[l][0]=0.f; s2[l][1]=0.f; s2[l][2]=0.f; s2[l][3]=0.f; }

        #pragma unroll 4
        for (int i = 0; i < 32; ++i) {
            const int e = eg * 32 + i;
            const float4 a  = eq4[(size_t)e * 128 + qq];
            const float  vv = vc_s[e];
            #pragma unroll
            for (int l = 0; l < 4; ++l) {
                const float kk = ek_s[l][e];
                s2[l][0] += vv * fast_rcp(a.x * kk + 1.0f);
                s2[l][1] += vv * fast_rcp(a.y * kk + 1.0f);
                s2[l][2] += vv * fast_rcp(a.z * kk + 1.0f);
                s2[l][3] += vv * fast_rcp(a.w * kk + 1.0f);
            }
        }

        #pragma unroll
        for (int l = 0; l < 4; ++l)
            *(float4*)&s2p_s[eg][l][qq * 4] =
                make_float4(s2[l][0], s2[l][1], s2[l][2], s2[l][3]);
        __syncthreads();

        const int w = tid >> 6, lane = tid & 63;
        const int l = w & 3, h2 = w >> 2, base = h2 * 256;
        float sjv[4];
        float m = -1e30f;
        #pragma unroll
        for (int i = 0; i < 4; ++i) {
            const int idx = base + lane + 64 * i;
            const float p = s2p_s[0][l][idx] + s2p_s[1][l][idx]
                          + s2p_s[2][l][idx] + s2p_s[3][l][idx];
            sjv[i] = vcsum - 2.0f * p;
            m = fmaxf(m, sjv[i]);
        }
        #pragma unroll
        for (int off = 32; off >= 1; off >>= 1) m = fmaxf(m, __shfl_xor(m, off));
        float Z = 0.f;
        #pragma unroll
        for (int i = 0; i < 4; ++i) {
            const int idx = base + lane + 64 * i;
            const float ex = __expf(sjv[i] - m);
            sj_s[l][idx] = ex;
            Z += ex;
        }
        #pragma unroll
        for (int off = 32; off >= 1; off >>= 1) Z += __shfl_xor(Z, off);
        if (lane == 0) mZ_s[l][h2] = make_float2(m, Z);
        __syncthreads();
        if (lane == 0) {
            const float2 A = mZ_s[l][0], B2 = mZ_s[l][1];
            const float M  = fmaxf(A.x, B2.x);
            const float Zt = A.y * __expf(A.x - M) + B2.y * __expf(B2.x - M);
            scale_s[l][h2] = __expf((h2 ? B2.x : A.x) - M) * fast_rcp(Zt);
        }
        __syncthreads();

        const int q = tid;
        #pragma unroll
        for (int li = 0; li < 4; ++li)
            attn[(size_t)(b * LK + l0 + li) * LQ + q] = sj_s[li][q] * scale_s[li][q >> 8];
        asm volatile("" ::: "memory");   // keep reps live
    }
}

// K3: context[b,l,:] = sum_q atten[b,l,q] * value[b,q,:]   (R2 baseline)
__global__ __launch_bounds__(1024) void context_kernel(
    const float* __restrict__ attn, const float* __restrict__ value,
    float* __restrict__ ctx)
{
    const int b    = blockIdx.x >> 6;
    const int lt   = blockIdx.x & 63;
    const int row0 = b * LK + lt * 8;
    const int tid  = threadIdx.x;
    const int g    = tid >> 6;
    const int lane = tid & 63;
    const float4* v4 = (const float4*)(value + (size_t)b * LQ * DD);
    __shared__ float4 red[8][8][64];   // 64 KB

    #pragma unroll 1
    for (int rep = 0; rep < REP_K3; ++rep) {
        __syncthreads();
        float4 ac[8];
        #pragma unroll
        for (int l = 0; l < 8; ++l) ac[l] = make_float4(0.f, 0.f, 0.f, 0.f);

        const int q0 = g * 32;
        for (int q = q0; q < q0 + 32; q += 4) {
            float4 a[8];
            #pragma unroll
            for (int l = 0; l < 8; ++l)
                a[l] = *(const float4*)(attn + (size_t)(row0 + l) * LQ + q);
            const float4 v0 = v4[(size_t)(q + 0) * 64 + lane];
            const float4 v1 = v4[(size_t)(q + 1) * 64 + lane];
            const float4 v2 = v4[(size_t)(q + 2) * 64 + lane];
            const float4 v3 = v4[(size_t)(q + 3) * 64 + lane];
            #pragma unroll
            for (int l = 0; l < 8; ++l) {
                ac[l].x += a[l].x * v0.x; ac[l].y += a[l].x * v0.y;
                ac[l].z += a[l].x * v0.z; ac[l].w += a[l].x * v0.w;
                ac[l].x += a[l].y * v1.x; ac[l].y += a[l].y * v1.y;
                ac[l].z += a[l].y * v1.z; ac[l].w += a[l].y * v1.w;
                ac[l].x += a[l].z * v2.x; ac[l].y += a[l].z * v2.y;
                ac[l].z += a[l].z * v2.z; ac[l].w += a[l].z * v2.w;
                ac[l].x += a[l].w * v3.x; ac[l].y += a[l].w * v3.y;
                ac[l].z += a[l].w * v3.z; ac[l].w += a[l].w * v3.w;
            }
        }

        if (g >= 8) {
            #pragma unroll
            for (int l = 0; l < 8; ++l) red[g - 8][l][lane] = ac[l];
        }
        __syncthreads();
        if (g < 8) {
            #pragma unroll
            for (int l = 0; l < 8; ++l) {
                const float4 r = red[g][l][lane];
                ac[l].x += r.x; ac[l].y += r.y; ac[l].z += r.z; ac[l].w += r.w;
            }
        }
        __syncthreads();
        if (g >= 4 && g < 8) {
            #pragma unroll
            for (int l = 0; l < 8; ++l) red[g - 4][l][lane] = ac[l];
        }
        __syncthreads();
        if (g < 4) {
            #pragma unroll
            for (int l = 0; l < 8; ++l) {
                const float4 r = red[g][l][lane];
                ac[l].x += r.x; ac[l].y += r.y; ac[l].z += r.z; ac[l].w += r.w;
            }
        }
        __syncthreads();
        if (g == 2 || g == 3) {
            #pragma unroll
            for (int l = 0; l < 8; ++l) red[g - 2][l][lane] = ac[l];
        }
        __syncthreads();
        if (g < 2) {
            #pragma unroll
            for (int l = 0; l < 8; ++l) {
                const float4 r = red[g][l][lane];
                ac[l].x += r.x; ac[l].y += r.y; ac[l].z += r.z; ac[l].w += r.w;
            }
        }
        __syncthreads();
        if (g == 1) {
            #pragma unroll
            for (int l = 0; l < 8; ++l) red[0][l][lane] = ac[l];
        }
        __syncthreads();
        if (g == 0) {
            #pragma unroll
            for (int l = 0; l < 8; ++l) {
                const float4 r = red[0][l][lane];
                ac[l].x += r.x; ac[l].y += r.y; ac[l].z += r.z; ac[l].w += r.w;
                ((float4*)ctx)[(size_t)(row0 + l) * 64 + lane] = ac[l];
            }
        }
        asm volatile("" ::: "memory");   // keep reps live
    }
}

extern "C" void kernel_launch(void* const* d_in, const int* in_sizes, int n_in,
                              void* d_out, int out_size, void* d_ws, size_t ws_size,
                              hipStream_t stream) {
    const float* query = (const float*)d_in[0];
    const float* key   = (const float*)d_in[1];
    const float* value = (const float*)d_in[2];
    const float* Wc1   = (const float*)d_in[3];
    const float* Wc2   = (const float*)d_in[4];
    const float* vc    = (const float*)d_in[5];

    float* ctx  = (float*)d_out;                          // [B, Lk, D]
    float* attn = (float*)d_out + (size_t)NB * LK * DD;   // [B, Lk, Lq]

    // Scratch aliases ctx region; safe only because of kernel boundaries
    // (K2 fully drains before K3 overwrites). d_ws is NOT used (re-poison race).
    float* EqT = ctx;                                     // [B, E, Lq]
    float* Ek  = ctx + (size_t)NB * LQ * EE;              // [B, Lk, E]

    proj_exp_kernel<<<dim3(512), dim3(256), 0, stream>>>(query, key, Wc1, Wc2, EqT, Ek);
    atten_kernel<<<dim3(NB * (LK / 4)), dim3(512), 0, stream>>>(EqT, Ek, vc, attn);
    context_kernel<<<dim3(NB * (LK / 8)), dim3(1024), 0, stream>>>(attn, value, ctx);
}

// Round 7
// 126.350 us; speedup vs baseline: 2.8141x; 2.8141x over previous
//
#include <hip/hip_runtime.h>

#define NB 4
#define LQ 512
#define LK 512
#define EE 128
#define DD 256

__device__ __forceinline__ float fast_rcp(float x) { return __builtin_amdgcn_rcpf(x); }

// K1: rows 0..2047 = query@Wc1 -> EqT[b][e][q] = exp(2q) TRANSPOSED;
//     rows 2048..4095 = key@Wc2 -> Ek[b][l][e] = exp(2k) row-major.
// 8 rows/block (512 blocks), 256 thr = 2 row-groups x 128 cols, 4 rows/thread.
// R5: d-step 16 -> 16 independent W loads in flight per step (was 8) to cover
// L2 latency at 2 waves/SIMD.
__global__ __launch_bounds__(256) void proj_exp_kernel(
    const float* __restrict__ query, const float* __restrict__ key,
    const float* __restrict__ Wc1, const float* __restrict__ Wc2,
    float* __restrict__ EqT, float* __restrict__ Ek)
{
    __shared__ float in_s[8][DD];   // 8 KB
    const int r0 = blockIdx.x * 8;
    const bool is_q = (r0 < NB * LQ);
    const float* src = is_q ? query : key;
    const float* W   = is_q ? Wc1   : Wc2;
    const int rbase  = is_q ? r0    : r0 - NB * LQ;

    const float4* srow4 = (const float4*)(src + (size_t)rbase * DD);
    #pragma unroll
    for (int i = 0; i < 2; ++i)
        ((float4*)in_s)[i * 256 + threadIdx.x] = srow4[i * 256 + threadIdx.x];
    __syncthreads();

    const int c  = threadIdx.x & 127;
    const int rg = threadIdx.x >> 7;   // 0..1 -> rows rg*4 .. rg*4+3 (wave-uniform)
    float acc[4] = {0.f, 0.f, 0.f, 0.f};
    #pragma unroll 1
    for (int d = 0; d < DD; d += 16) {
        float w[16];
        #pragma unroll
        for (int j = 0; j < 16; ++j) w[j] = W[(d + j) * EE + c];
        #pragma unroll
        for (int i = 0; i < 4; ++i) {
            const float4 xa = *(const float4*)&in_s[rg * 4 + i][d];       // broadcast
            const float4 xb = *(const float4*)&in_s[rg * 4 + i][d + 4];
            const float4 xc = *(const float4*)&in_s[rg * 4 + i][d + 8];
            const float4 xd = *(const float4*)&in_s[rg * 4 + i][d + 12];
            acc[i] += xa.x * w[0]  + xa.y * w[1]  + xa.z * w[2]  + xa.w * w[3]
                    + xb.x * w[4]  + xb.y * w[5]  + xb.z * w[6]  + xb.w * w[7]
                    + xc.x * w[8]  + xc.y * w[9]  + xc.z * w[10] + xc.w * w[11]
                    + xd.x * w[12] + xd.y * w[13] + xd.z * w[14] + xd.w * w[15];
        }
    }
    if (is_q) {
        const int b    = rbase >> 9;
        const int qloc = (rbase & 511) + rg * 4;
        float4 o;
        o.x = __expf(2.0f * acc[0]); o.y = __expf(2.0f * acc[1]);
        o.z = __expf(2.0f * acc[2]); o.w = __expf(2.0f * acc[3]);
        *(float4*)&EqT[((size_t)(b * EE + c)) * LQ + qloc] = o;
    } else {
        #pragma unroll
        for (int i = 0; i < 4; ++i)
            Ek[(size_t)(rbase + rg * 4 + i) * EE + c] = __expf(2.0f * acc[i]);
    }
}

// K2: block = (b, 4 l-rows), 512 threads. Trans-pipe-bound (~6.8us floor:
// 134M v_rcp at 8cyc/wave). R5: unroll 8 for deeper EqT prefetch.
__global__ __launch_bounds__(512) void atten_kernel(
    const float* __restrict__ EqT, const float* __restrict__ Ek,
    const float* __restrict__ vc, float* __restrict__ attn)
{
    __shared__ float  ek_s[4][EE];      // 2 KB
    __shared__ float  vc_s[EE];         // 0.5 KB
    __shared__ float  s2p_s[4][4][LQ];  // 32 KB (partials from all 4 e-groups)
    __shared__ float  sj_s[4][LQ];      // 8 KB
    __shared__ float2 mZ_s[4][2];
    __shared__ float  scale_s[4][2];
    const int b   = blockIdx.x >> 7;
    const int lt  = blockIdx.x & 127;
    const int l0  = lt * 4;
    const int tid = threadIdx.x;
    const int qq  = tid & 127;          // q-quad
    const int eg  = tid >> 7;           // e-group

    ((float*)ek_s)[tid] = Ek[((size_t)b * LK + l0) * EE + tid];   // coalesced
    if (tid < EE) vc_s[tid] = vc[tid];
    __syncthreads();

    float vcsum = 0.f;
    #pragma unroll
    for (int e = 0; e < EE; e += 4) {
        const float4 v = *(const float4*)&vc_s[e];
        vcsum += (v.x + v.y) + (v.z + v.w);
    }

    const float4* eq4 = (const float4*)(EqT + (size_t)b * EE * LQ);
    float s2[4][4];
    #pragma unroll
    for (int l = 0; l < 4; ++l) { s2[l][0]=0.f; s2[l][1]=0.f; s2[l][2]=0.f; s2[l][3]=0.f; }

    #pragma unroll 8
    for (int i = 0; i < 32; ++i) {
        const int e = eg * 32 + i;
        const float4 a  = eq4[(size_t)e * 128 + qq];   // coalesced float4
        const float  vv = vc_s[e];                     // broadcast
        #pragma unroll
        for (int l = 0; l < 4; ++l) {
            const float kk = ek_s[l][e];               // broadcast
            s2[l][0] += vv * fast_rcp(a.x * kk + 1.0f);
            s2[l][1] += vv * fast_rcp(a.y * kk + 1.0f);
            s2[l][2] += vv * fast_rcp(a.z * kk + 1.0f);
            s2[l][3] += vv * fast_rcp(a.w * kk + 1.0f);
        }
    }

    // every e-group parks its partials; combine fused into softmax max-pass
    #pragma unroll
    for (int l = 0; l < 4; ++l)
        *(float4*)&s2p_s[eg][l][qq * 4] =
            make_float4(s2[l][0], s2[l][1], s2[l][2], s2[l][3]);
    __syncthreads();

    // softmax over q: wave w handles (l = w&3, q-half h2 = w>>2)
    const int w = tid >> 6, lane = tid & 63;
    const int l = w & 3, h2 = w >> 2, base = h2 * 256;
    float sjv[4];
    float m = -1e30f;
    #pragma unroll
    for (int i = 0; i < 4; ++i) {
        const int idx = base + lane + 64 * i;
        const float p = s2p_s[0][l][idx] + s2p_s[1][l][idx]
                      + s2p_s[2][l][idx] + s2p_s[3][l][idx];
        sjv[i] = vcsum - 2.0f * p;
        m = fmaxf(m, sjv[i]);
    }
    #pragma unroll
    for (int off = 32; off >= 1; off >>= 1) m = fmaxf(m, __shfl_xor(m, off));
    float Z = 0.f;
    #pragma unroll
    for (int i = 0; i < 4; ++i) {
        const int idx = base + lane + 64 * i;
        const float ex = __expf(sjv[i] - m);
        sj_s[l][idx] = ex;                                    // lane-exclusive
        Z += ex;
    }
    #pragma unroll
    for (int off = 32; off >= 1; off >>= 1) Z += __shfl_xor(Z, off);
    if (lane == 0) mZ_s[l][h2] = make_float2(m, Z);
    __syncthreads();
    if (lane == 0) {
        const float2 A = mZ_s[l][0], B2 = mZ_s[l][1];
        const float M  = fmaxf(A.x, B2.x);
        const float Zt = A.y * __expf(A.x - M) + B2.y * __expf(B2.x - M);
        scale_s[l][h2] = __expf((h2 ? B2.x : A.x) - M) * fast_rcp(Zt);
    }
    __syncthreads();

    const int q = tid;
    #pragma unroll
    for (int li = 0; li < 4; ++li)
        attn[(size_t)(b * LK + l0 + li) * LQ + q] = sj_s[li][q] * scale_s[li][q >> 8];
}

// K3: context[b,l,:] = sum_q atten[b,l,q] * value[b,q,:]
// R5 fix (from counters: 14.6us/rep, VALUBusy 34% => ~10us latency stall on
// 8 uniform-address GLOBAL attn loads per q-step): stage the block's 8x512
// attn tile in LDS once (16 KB, coalesced), inner loop uses same-address
// ds_read broadcasts instead. 80 KB LDS total, 1 block/CU (grid==256 anyway).
__global__ __launch_bounds__(1024) void context_kernel(
    const float* __restrict__ attn, const float* __restrict__ value,
    float* __restrict__ ctx)
{
    const int b    = blockIdx.x >> 6;
    const int lt   = blockIdx.x & 63;
    const int row0 = b * LK + lt * 8;
    const int tid  = threadIdx.x;
    const int g    = tid >> 6;      // q-group 0..15 -> q in [g*32, g*32+32)
    const int lane = tid & 63;      // d float4 chunk
    const float4* v4 = (const float4*)(value + (size_t)b * LQ * DD);

    __shared__ float  s_attn[8][LQ];   // 16 KB
    __shared__ float4 red[8][8][64];   // 64 KB

    // stage attn tile: 4096 floats, one float4 per thread, coalesced
    {
        const int r  = tid >> 7;        // row 0..7
        const int c4 = tid & 127;       // float4 col
        *(float4*)&s_attn[r][c4 * 4] =
            *(const float4*)(attn + (size_t)(row0 + r) * LQ + c4 * 4);
    }
    __syncthreads();

    float4 ac[8];
    #pragma unroll
    for (int l = 0; l < 8; ++l) ac[l] = make_float4(0.f, 0.f, 0.f, 0.f);

    const int q0 = g * 32;
    for (int q = q0; q < q0 + 32; q += 4) {
        float4 a[8];
        #pragma unroll
        for (int l = 0; l < 8; ++l)
            a[l] = *(const float4*)&s_attn[l][q];                 // LDS broadcast
        const float4 v0 = v4[(size_t)(q + 0) * 64 + lane];        // coalesced
        const float4 v1 = v4[(size_t)(q + 1) * 64 + lane];
        const float4 v2 = v4[(size_t)(q + 2) * 64 + lane];
        const float4 v3 = v4[(size_t)(q + 3) * 64 + lane];
        #pragma unroll
        for (int l = 0; l < 8; ++l) {
            ac[l].x += a[l].x * v0.x; ac[l].y += a[l].x * v0.y;
            ac[l].z += a[l].x * v0.z; ac[l].w += a[l].x * v0.w;
            ac[l].x += a[l].y * v1.x; ac[l].y += a[l].y * v1.y;
            ac[l].z += a[l].y * v1.z; ac[l].w += a[l].y * v1.w;
            ac[l].x += a[l].z * v2.x; ac[l].y += a[l].z * v2.y;
            ac[l].z += a[l].z * v2.z; ac[l].w += a[l].z * v2.w;
            ac[l].x += a[l].w * v3.x; ac[l].y += a[l].w * v3.y;
            ac[l].z += a[l].w * v3.z; ac[l].w += a[l].w * v3.w;
        }
    }

    // tree reduce over the 16 q-groups: 16 -> 8 -> 4 -> 2 -> 1
    if (g >= 8) {
        #pragma unroll
        for (int l = 0; l < 8; ++l) red[g - 8][l][lane] = ac[l];
    }
    __syncthreads();
    if (g < 8) {
        #pragma unroll
        for (int l = 0; l < 8; ++l) {
            const float4 r = red[g][l][lane];
            ac[l].x += r.x; ac[l].y += r.y; ac[l].z += r.z; ac[l].w += r.w;
        }
    }
    __syncthreads();
    if (g >= 4 && g < 8) {
        #pragma unroll
        for (int l = 0; l < 8; ++l) red[g - 4][l][lane] = ac[l];
    }
    __syncthreads();
    if (g < 4) {
        #pragma unroll
        for (int l = 0; l < 8; ++l) {
            const float4 r = red[g][l][lane];
            ac[l].x += r.x; ac[l].y += r.y; ac[l].z += r.z; ac[l].w += r.w;
        }
    }
    __syncthreads();
    if (g == 2 || g == 3) {
        #pragma unroll
        for (int l = 0; l < 8; ++l) red[g - 2][l][lane] = ac[l];
    }
    __syncthreads();
    if (g < 2) {
        #pragma unroll
        for (int l = 0; l < 8; ++l) {
            const float4 r = red[g][l][lane];
            ac[l].x += r.x; ac[l].y += r.y; ac[l].z += r.z; ac[l].w += r.w;
        }
    }
    __syncthreads();
    if (g == 1) {
        #pragma unroll
        for (int l = 0; l < 8; ++l) red[0][l][lane] = ac[l];
    }
    __syncthreads();
    if (g == 0) {
        #pragma unroll
        for (int l = 0; l < 8; ++l) {
            const float4 r = red[0][l][lane];
            ac[l].x += r.x; ac[l].y += r.y; ac[l].z += r.z; ac[l].w += r.w;
            ((float4*)ctx)[(size_t)(row0 + l) * 64 + lane] = ac[l];
        }
    }
}

extern "C" void kernel_launch(void* const* d_in, const int* in_sizes, int n_in,
                              void* d_out, int out_size, void* d_ws, size_t ws_size,
                              hipStream_t stream) {
    const float* query = (const float*)d_in[0];
    const float* key   = (const float*)d_in[1];
    const float* value = (const float*)d_in[2];
    const float* Wc1   = (const float*)d_in[3];
    const float* Wc2   = (const float*)d_in[4];
    const float* vc    = (const float*)d_in[5];

    float* ctx  = (float*)d_out;                          // [B, Lk, D]
    float* attn = (float*)d_out + (size_t)NB * LK * DD;   // [B, Lk, Lq]

    // Scratch aliases ctx region; safe only because of kernel boundaries
    // (K2 fully drains before K3 overwrites). d_ws is NOT used (re-poison race).
    float* EqT = ctx;                                     // [B, E, Lq]
    float* Ek  = ctx + (size_t)NB * LQ * EE;              // [B, Lk, E]

    proj_exp_kernel<<<dim3(512), dim3(256), 0, stream>>>(query, key, Wc1, Wc2, EqT, Ek);
    atten_kernel<<<dim3(NB * (LK / 4)), dim3(512), 0, stream>>>(EqT, Ek, vc, attn);
    context_kernel<<<dim3(NB * (LK / 8)), dim3(1024), 0, stream>>>(attn, value, ctx);
}

// Round 8
// 118.828 us; speedup vs baseline: 2.9922x; 1.0633x over previous
//
#include <hip/hip_runtime.h>

#define NB 4
#define LQ 512
#define LK 512
#define EE 128
#define DD 256

__device__ __forceinline__ float fast_rcp(float x) { return __builtin_amdgcn_rcpf(x); }

// K1: rows 0..2047 = query@Wc1 -> EqT[b][e][q] = exp(2q) TRANSPOSED;
//     rows 2048..4095 = key@Wc2 -> Ek[b][l][e] = exp(2k) row-major.
// 8 rows/block (512 blocks), 256 thr. EXACT R2 version (R5's d16 variant was
// part of a bundle that net-regressed; reverted pending per-kernel counters).
__global__ __launch_bounds__(256) void proj_exp_kernel(
    const float* __restrict__ query, const float* __restrict__ key,
    const float* __restrict__ Wc1, const float* __restrict__ Wc2,
    float* __restrict__ EqT, float* __restrict__ Ek)
{
    __shared__ float in_s[8][DD];   // 8 KB
    const int r0 = blockIdx.x * 8;
    const bool is_q = (r0 < NB * LQ);
    const float* src = is_q ? query : key;
    const float* W   = is_q ? Wc1   : Wc2;
    const int rbase  = is_q ? r0    : r0 - NB * LQ;

    const float4* srow4 = (const float4*)(src + (size_t)rbase * DD);
    #pragma unroll
    for (int i = 0; i < 2; ++i)
        ((float4*)in_s)[i * 256 + threadIdx.x] = srow4[i * 256 + threadIdx.x];
    __syncthreads();

    const int c  = threadIdx.x & 127;
    const int rg = threadIdx.x >> 7;   // 0..1 -> rows rg*4 .. rg*4+3 (wave-uniform)
    float acc[4] = {0.f, 0.f, 0.f, 0.f};
    for (int d = 0; d < DD; d += 8) {
        const float w0 = W[(d + 0) * EE + c];
        const float w1 = W[(d + 1) * EE + c];
        const float w2 = W[(d + 2) * EE + c];
        const float w3 = W[(d + 3) * EE + c];
        const float w4 = W[(d + 4) * EE + c];
        const float w5 = W[(d + 5) * EE + c];
        const float w6 = W[(d + 6) * EE + c];
        const float w7 = W[(d + 7) * EE + c];
        #pragma unroll
        for (int i = 0; i < 4; ++i) {
            const float4 xa = *(const float4*)&in_s[rg * 4 + i][d];      // broadcast
            const float4 xb = *(const float4*)&in_s[rg * 4 + i][d + 4];
            acc[i] += xa.x * w0 + xa.y * w1 + xa.z * w2 + xa.w * w3
                    + xb.x * w4 + xb.y * w5 + xb.z * w6 + xb.w * w7;
        }
    }
    if (is_q) {
        const int b    = rbase >> 9;
        const int qloc = (rbase & 511) + rg * 4;
        float4 o;
        o.x = __expf(2.0f * acc[0]); o.y = __expf(2.0f * acc[1]);
        o.z = __expf(2.0f * acc[2]); o.w = __expf(2.0f * acc[3]);
        *(float4*)&EqT[((size_t)(b * EE + c)) * LQ + qloc] = o;
    } else {
        #pragma unroll
        for (int i = 0; i < 4; ++i)
            Ek[(size_t)(rbase + rg * 4 + i) * EE + c] = __expf(2.0f * acc[i]);
    }
}

// K2: block = (b, 4 l-rows), 512 threads. EXACT R2 version (unroll 4; R5's
// unroll-8 reverted as part of the regression bundle).
__global__ __launch_bounds__(512) void atten_kernel(
    const float* __restrict__ EqT, const float* __restrict__ Ek,
    const float* __restrict__ vc, float* __restrict__ attn)
{
    __shared__ float  ek_s[4][EE];      // 2 KB
    __shared__ float  vc_s[EE];         // 0.5 KB
    __shared__ float  s2p_s[4][4][LQ];  // 32 KB (partials from all 4 e-groups)
    __shared__ float  sj_s[4][LQ];      // 8 KB
    __shared__ float2 mZ_s[4][2];
    __shared__ float  scale_s[4][2];
    const int b   = blockIdx.x >> 7;
    const int lt  = blockIdx.x & 127;
    const int l0  = lt * 4;
    const int tid = threadIdx.x;
    const int qq  = tid & 127;          // q-quad
    const int eg  = tid >> 7;           // e-group

    ((float*)ek_s)[tid] = Ek[((size_t)b * LK + l0) * EE + tid];   // coalesced
    if (tid < EE) vc_s[tid] = vc[tid];
    __syncthreads();

    float vcsum = 0.f;
    #pragma unroll
    for (int e = 0; e < EE; e += 4) {
        const float4 v = *(const float4*)&vc_s[e];
        vcsum += (v.x + v.y) + (v.z + v.w);
    }

    const float4* eq4 = (const float4*)(EqT + (size_t)b * EE * LQ);
    float s2[4][4];
    #pragma unroll
    for (int l = 0; l < 4; ++l) { s2[l][0]=0.f; s2[l][1]=0.f; s2[l][2]=0.f; s2[l][3]=0.f; }

    #pragma unroll 4
    for (int i = 0; i < 32; ++i) {
        const int e = eg * 32 + i;
        const float4 a  = eq4[(size_t)e * 128 + qq];   // coalesced float4
        const float  vv = vc_s[e];                     // broadcast
        #pragma unroll
        for (int l = 0; l < 4; ++l) {
            const float kk = ek_s[l][e];               // broadcast
            s2[l][0] += vv * fast_rcp(a.x * kk + 1.0f);
            s2[l][1] += vv * fast_rcp(a.y * kk + 1.0f);
            s2[l][2] += vv * fast_rcp(a.z * kk + 1.0f);
            s2[l][3] += vv * fast_rcp(a.w * kk + 1.0f);
        }
    }

    // every e-group parks its partials; combine fused into softmax max-pass
    #pragma unroll
    for (int l = 0; l < 4; ++l)
        *(float4*)&s2p_s[eg][l][qq * 4] =
            make_float4(s2[l][0], s2[l][1], s2[l][2], s2[l][3]);
    __syncthreads();

    // softmax over q: wave w handles (l = w&3, q-half h2 = w>>2)
    const int w = tid >> 6, lane = tid & 63;
    const int l = w & 3, h2 = w >> 2, base = h2 * 256;
    float sjv[4];
    float m = -1e30f;
    #pragma unroll
    for (int i = 0; i < 4; ++i) {
        const int idx = base + lane + 64 * i;
        const float p = s2p_s[0][l][idx] + s2p_s[1][l][idx]
                      + s2p_s[2][l][idx] + s2p_s[3][l][idx];
        sjv[i] = vcsum - 2.0f * p;
        m = fmaxf(m, sjv[i]);
    }
    #pragma unroll
    for (int off = 32; off >= 1; off >>= 1) m = fmaxf(m, __shfl_xor(m, off));
    float Z = 0.f;
    #pragma unroll
    for (int i = 0; i < 4; ++i) {
        const int idx = base + lane + 64 * i;
        const float ex = __expf(sjv[i] - m);
        sj_s[l][idx] = ex;                                    // lane-exclusive
        Z += ex;
    }
    #pragma unroll
    for (int off = 32; off >= 1; off >>= 1) Z += __shfl_xor(Z, off);
    if (lane == 0) mZ_s[l][h2] = make_float2(m, Z);
    __syncthreads();
    if (lane == 0) {
        const float2 A = mZ_s[l][0], B2 = mZ_s[l][1];
        const float M  = fmaxf(A.x, B2.x);
        const float Zt = A.y * __expf(A.x - M) + B2.y * __expf(B2.x - M);
        scale_s[l][h2] = __expf((h2 ? B2.x : A.x) - M) * fast_rcp(Zt);
    }
    __syncthreads();

    const int q = tid;
    #pragma unroll
    for (int li = 0; li < 4; ++li)
        attn[(size_t)(b * LK + l0 + li) * LQ + q] = sj_s[li][q] * scale_s[li][q >> 8];
}

// K3: context[b,l,:] = sum_q atten[b,l,q] * value[b,q,:]
// Counter-driven fix (R5 profile: 14.6us, VALUBusy 34% => ~10us latency stall):
// (a) attn tile staged in LDS once (uniform-address global loads -> ds_read
//     broadcasts); (b) value loads software-pipelined: next 4 float4 issued
//     BEFORE the FMA block consuming the current 4 (doubles in-flight depth
//     per thread; 4 loads x 4 waves/SIMD was too shallow for ~250cy L2 lat).
__global__ __launch_bounds__(1024) void context_kernel(
    const float* __restrict__ attn, const float* __restrict__ value,
    float* __restrict__ ctx)
{
    const int b    = blockIdx.x >> 6;
    const int lt   = blockIdx.x & 63;
    const int row0 = b * LK + lt * 8;
    const int tid  = threadIdx.x;
    const int g    = tid >> 6;      // q-group 0..15 -> q in [g*32, g*32+32)
    const int lane = tid & 63;      // d float4 chunk
    const float4* v4 = (const float4*)(value + (size_t)b * LQ * DD);

    __shared__ float  s_attn[8][LQ];   // 16 KB
    __shared__ float4 red[8][8][64];   // 64 KB

    // stage attn tile: 4096 floats, one float4 per thread, coalesced
    {
        const int r  = tid >> 7;        // row 0..7
        const int c4 = tid & 127;       // float4 col
        *(float4*)&s_attn[r][c4 * 4] =
            *(const float4*)(attn + (size_t)(row0 + r) * LQ + c4 * 4);
    }
    __syncthreads();

    float4 ac[8];
    #pragma unroll
    for (int l = 0; l < 8; ++l) ac[l] = make_float4(0.f, 0.f, 0.f, 0.f);

    const int q0 = g * 32;
    float4 v0 = v4[(size_t)(q0 + 0) * 64 + lane];
    float4 v1 = v4[(size_t)(q0 + 1) * 64 + lane];
    float4 v2 = v4[(size_t)(q0 + 2) * 64 + lane];
    float4 v3 = v4[(size_t)(q0 + 3) * 64 + lane];
    #pragma unroll
    for (int qs = 0; qs < 8; ++qs) {
        const int q = q0 + qs * 4;
        float4 n0, n1, n2, n3;
        if (qs < 7) {                                          // prefetch next step
            n0 = v4[(size_t)(q + 4) * 64 + lane];
            n1 = v4[(size_t)(q + 5) * 64 + lane];
            n2 = v4[(size_t)(q + 6) * 64 + lane];
            n3 = v4[(size_t)(q + 7) * 64 + lane];
        }
        float4 a[8];
        #pragma unroll
        for (int l = 0; l < 8; ++l)
            a[l] = *(const float4*)&s_attn[l][q];              // LDS broadcast
        #pragma unroll
        for (int l = 0; l < 8; ++l) {
            ac[l].x += a[l].x * v0.x; ac[l].y += a[l].x * v0.y;
            ac[l].z += a[l].x * v0.z; ac[l].w += a[l].x * v0.w;
            ac[l].x += a[l].y * v1.x; ac[l].y += a[l].y * v1.y;
            ac[l].z += a[l].y * v1.z; ac[l].w += a[l].y * v1.w;
            ac[l].x += a[l].z * v2.x; ac[l].y += a[l].z * v2.y;
            ac[l].z += a[l].z * v2.z; ac[l].w += a[l].z * v2.w;
            ac[l].x += a[l].w * v3.x; ac[l].y += a[l].w * v3.y;
            ac[l].z += a[l].w * v3.z; ac[l].w += a[l].w * v3.w;
        }
        if (qs < 7) { v0 = n0; v1 = n1; v2 = n2; v3 = n3; }
    }

    // tree reduce over the 16 q-groups: 16 -> 8 -> 4 -> 2 -> 1
    if (g >= 8) {
        #pragma unroll
        for (int l = 0; l < 8; ++l) red[g - 8][l][lane] = ac[l];
    }
    __syncthreads();
    if (g < 8) {
        #pragma unroll
        for (int l = 0; l < 8; ++l) {
            const float4 r = red[g][l][lane];
            ac[l].x += r.x; ac[l].y += r.y; ac[l].z += r.z; ac[l].w += r.w;
        }
    }
    __syncthreads();
    if (g >= 4 && g < 8) {
        #pragma unroll
        for (int l = 0; l < 8; ++l) red[g - 4][l][lane] = ac[l];
    }
    __syncthreads();
    if (g < 4) {
        #pragma unroll
        for (int l = 0; l < 8; ++l) {
            const float4 r = red[g][l][lane];
            ac[l].x += r.x; ac[l].y += r.y; ac[l].z += r.z; ac[l].w += r.w;
        }
    }
    __syncthreads();
    if (g == 2 || g == 3) {
        #pragma unroll
        for (int l = 0; l < 8; ++l) red[g - 2][l][lane] = ac[l];
    }
    __syncthreads();
    if (g < 2) {
        #pragma unroll
        for (int l = 0; l < 8; ++l) {
            const float4 r = red[g][l][lane];
            ac[l].x += r.x; ac[l].y += r.y; ac[l].z += r.z; ac[l].w += r.w;
        }
    }
    __syncthreads();
    if (g == 1) {
        #pragma unroll
        for (int l = 0; l < 8; ++l) red[0][l][lane] = ac[l];
    }
    __syncthreads();
    if (g == 0) {
        #pragma unroll
        for (int l = 0; l < 8; ++l) {
            const float4 r = red[0][l][lane];
            ac[l].x += r.x; ac[l].y += r.y; ac[l].z += r.z; ac[l].w += r.w;
            ((float4*)ctx)[(size_t)(row0 + l) * 64 + lane] = ac[l];
        }
    }
}

extern "C" void kernel_launch(void* const* d_in, const int* in_sizes, int n_in,
                              void* d_out, int out_size, void* d_ws, size_t ws_size,
                              hipStream_t stream) {
    const float* query = (const float*)d_in[0];
    const float* key   = (const float*)d_in[1];
    const float* value = (const float*)d_in[2];
    const float* Wc1   = (const float*)d_in[3];
    const float* Wc2   = (const float*)d_in[4];
    const float* vc    = (const float*)d_in[5];

    float* ctx  = (float*)d_out;                          // [B, Lk, D]
    float* attn = (float*)d_out + (size_t)NB * LK * DD;   // [B, Lk, Lq]

    // Scratch aliases ctx region; safe ONLY because of kernel boundaries
    // (K2 fully drains before K3 overwrites). Fusing K2+K3 is impossible:
    // live-peak attn(4MB)+ctx(2MB)+EqT/Ek(2MB) > 6MB out buffer, d_ws races
    // (prior session), grid barriers falsified (R3: 240us). 3 dispatches is
    // structurally forced.
    float* EqT = ctx;                                     // [B, E, Lq]
    float* Ek  = ctx + (size_t)NB * LQ * EE;              // [B, Lk, E]

    proj_exp_kernel<<<dim3(512), dim3(256), 0, stream>>>(query, key, Wc1, Wc2, EqT, Ek);
    atten_kernel<<<dim3(NB * (LK / 4)), dim3(512), 0, stream>>>(EqT, Ek, vc, attn);
    context_kernel<<<dim3(NB * (LK / 8)), dim3(1024), 0, stream>>>(attn, value, ctx);
}

// Round 10
// 115.246 us; speedup vs baseline: 3.0853x; 1.0311x over previous
//
#include <hip/hip_runtime.h>

#define NB 4
#define LQ 512
#define LK 512
#define EE 128
#define DD 256

__device__ __forceinline__ float fast_rcp(float x) { return __builtin_amdgcn_rcpf(x); }

// K1: rows 0..2047 = query@Wc1 -> EqT[b][e][q] = exp(2q) TRANSPOSED;
//     rows 2048..4095 = key@Wc2 -> Ek[b][l][e] = exp(2k) row-major.
// R8 change (single variable): 4 rows/block (was 8) -> 1024 blocks -> 4 blocks/CU
// = 4 waves/SIMD (was 2). Doubles TLP to hide W-column L2 latency; W re-read
// traffic doubles to 128MB L2 (~3.7us at 34.5TB/s, still cheap). Per-row math
// order identical -> bit-identical output.
__global__ __launch_bounds__(256) void proj_exp_kernel(
    const float* __restrict__ query, const float* __restrict__ key,
    const float* __restrict__ Wc1, const float* __restrict__ Wc2,
    float* __restrict__ EqT, float* __restrict__ Ek)
{
    __shared__ float in_s[4][DD];   // 4 KB
    const int r0 = blockIdx.x * 4;
    const bool is_q = (r0 < NB * LQ);
    const float* src = is_q ? query : key;
    const float* W   = is_q ? Wc1   : Wc2;
    const int rbase  = is_q ? r0    : r0 - NB * LQ;

    // stage 4 rows = 1024 floats = 256 float4, one per thread, coalesced
    ((float4*)in_s)[threadIdx.x] =
        ((const float4*)(src + (size_t)rbase * DD))[threadIdx.x];
    __syncthreads();

    const int c  = threadIdx.x & 127;
    const int rg = threadIdx.x >> 7;   // 0..1 -> rows rg*2, rg*2+1 (wave-uniform)
    float acc[2] = {0.f, 0.f};
    for (int d = 0; d < DD; d += 8) {
        const float w0 = W[(d + 0) * EE + c];
        const float w1 = W[(d + 1) * EE + c];
        const float w2 = W[(d + 2) * EE + c];
        const float w3 = W[(d + 3) * EE + c];
        const float w4 = W[(d + 4) * EE + c];
        const float w5 = W[(d + 5) * EE + c];
        const float w6 = W[(d + 6) * EE + c];
        const float w7 = W[(d + 7) * EE + c];
        #pragma unroll
        for (int i = 0; i < 2; ++i) {
            const float4 xa = *(const float4*)&in_s[rg * 2 + i][d];      // broadcast
            const float4 xb = *(const float4*)&in_s[rg * 2 + i][d + 4];
            acc[i] += xa.x * w0 + xa.y * w1 + xa.z * w2 + xa.w * w3
                    + xb.x * w4 + xb.y * w5 + xb.z * w6 + xb.w * w7;
        }
    }
    if (is_q) {
        const int b    = rbase >> 9;                 // 4-row block never straddles b
        const int qloc = (rbase & 511) + rg * 2;
        float2 o;
        o.x = __expf(2.0f * acc[0]);
        o.y = __expf(2.0f * acc[1]);
        *(float2*)&EqT[((size_t)(b * EE + c)) * LQ + qloc] = o;
    } else {
        #pragma unroll
        for (int i = 0; i < 2; ++i)
            Ek[(size_t)(rbase + rg * 2 + i) * EE + c] = __expf(2.0f * acc[i]);
    }
}

// K2: block = (b, 4 l-rows), 512 threads. EXACT R2 version (proven in 118.8 best).
__global__ __launch_bounds__(512) void atten_kernel(
    const float* __restrict__ EqT, const float* __restrict__ Ek,
    const float* __restrict__ vc, float* __restrict__ attn)
{
    __shared__ float  ek_s[4][EE];      // 2 KB
    __shared__ float  vc_s[EE];         // 0.5 KB
    __shared__ float  s2p_s[4][4][LQ];  // 32 KB (partials from all 4 e-groups)
    __shared__ float  sj_s[4][LQ];      // 8 KB
    __shared__ float2 mZ_s[4][2];
    __shared__ float  scale_s[4][2];
    const int b   = blockIdx.x >> 7;
    const int lt  = blockIdx.x & 127;
    const int l0  = lt * 4;
    const int tid = threadIdx.x;
    const int qq  = tid & 127;          // q-quad
    const int eg  = tid >> 7;           // e-group

    ((float*)ek_s)[tid] = Ek[((size_t)b * LK + l0) * EE + tid];   // coalesced
    if (tid < EE) vc_s[tid] = vc[tid];
    __syncthreads();

    float vcsum = 0.f;
    #pragma unroll
    for (int e = 0; e < EE; e += 4) {
        const float4 v = *(const float4*)&vc_s[e];
        vcsum += (v.x + v.y) + (v.z + v.w);
    }

    const float4* eq4 = (const float4*)(EqT + (size_t)b * EE * LQ);
    float s2[4][4];
    #pragma unroll
    for (int l = 0; l < 4; ++l) { s2[l][0]=0.f; s2[l][1]=0.f; s2[l][2]=0.f; s2[l][3]=0.f; }

    #pragma unroll 4
    for (int i = 0; i < 32; ++i) {
        const int e = eg * 32 + i;
        const float4 a  = eq4[(size_t)e * 128 + qq];   // coalesced float4
        const float  vv = vc_s[e];                     // broadcast
        #pragma unroll
        for (int l = 0; l < 4; ++l) {
            const float kk = ek_s[l][e];               // broadcast
            s2[l][0] += vv * fast_rcp(a.x * kk + 1.0f);
            s2[l][1] += vv * fast_rcp(a.y * kk + 1.0f);
            s2[l][2] += vv * fast_rcp(a.z * kk + 1.0f);
            s2[l][3] += vv * fast_rcp(a.w * kk + 1.0f);
        }
    }

    // every e-group parks its partials; combine fused into softmax max-pass
    #pragma unroll
    for (int l = 0; l < 4; ++l)
        *(float4*)&s2p_s[eg][l][qq * 4] =
            make_float4(s2[l][0], s2[l][1], s2[l][2], s2[l][3]);
    __syncthreads();

    // softmax over q: wave w handles (l = w&3, q-half h2 = w>>2)
    const int w = tid >> 6, lane = tid & 63;
    const int l = w & 3, h2 = w >> 2, base = h2 * 256;
    float sjv[4];
    float m = -1e30f;
    #pragma unroll
    for (int i = 0; i < 4; ++i) {
        const int idx = base + lane + 64 * i;
        const float p = s2p_s[0][l][idx] + s2p_s[1][l][idx]
                      + s2p_s[2][l][idx] + s2p_s[3][l][idx];
        sjv[i] = vcsum - 2.0f * p;
        m = fmaxf(m, sjv[i]);
    }
    #pragma unroll
    for (int off = 32; off >= 1; off >>= 1) m = fmaxf(m, __shfl_xor(m, off));
    float Z = 0.f;
    #pragma unroll
    for (int i = 0; i < 4; ++i) {
        const int idx = base + lane + 64 * i;
        const float ex = __expf(sjv[i] - m);
        sj_s[l][idx] = ex;                                    // lane-exclusive
        Z += ex;
    }
    #pragma unroll
    for (int off = 32; off >= 1; off >>= 1) Z += __shfl_xor(Z, off);
    if (lane == 0) mZ_s[l][h2] = make_float2(m, Z);
    __syncthreads();
    if (lane == 0) {
        const float2 A = mZ_s[l][0], B2 = mZ_s[l][1];
        const float M  = fmaxf(A.x, B2.x);
        const float Zt = A.y * __expf(A.x - M) + B2.y * __expf(B2.x - M);
        scale_s[l][h2] = __expf((h2 ? B2.x : A.x) - M) * fast_rcp(Zt);
    }
    __syncthreads();

    const int q = tid;
    #pragma unroll
    for (int li = 0; li < 4; ++li)
        attn[(size_t)(b * LK + l0 + li) * LQ + q] = sj_s[li][q] * scale_s[li][q >> 8];
}

// K3: context[b,l,:] = sum_q atten[b,l,q] * value[b,q,:]   (R8 best version:
// attn tile in LDS + value loads software-pipelined one step ahead)
__global__ __launch_bounds__(1024) void context_kernel(
    const float* __restrict__ attn, const float* __restrict__ value,
    float* __restrict__ ctx)
{
    const int b    = blockIdx.x >> 6;
    const int lt   = blockIdx.x & 63;
    const int row0 = b * LK + lt * 8;
    const int tid  = threadIdx.x;
    const int g    = tid >> 6;      // q-group 0..15 -> q in [g*32, g*32+32)
    const int lane = tid & 63;      // d float4 chunk
    const float4* v4 = (const float4*)(value + (size_t)b * LQ * DD);

    __shared__ float  s_attn[8][LQ];   // 16 KB
    __shared__ float4 red[8][8][64];   // 64 KB

    // stage attn tile: 4096 floats, one float4 per thread, coalesced
    {
        const int r  = tid >> 7;        // row 0..7
        const int c4 = tid & 127;       // float4 col
        *(float4*)&s_attn[r][c4 * 4] =
            *(const float4*)(attn + (size_t)(row0 + r) * LQ + c4 * 4);
    }
    __syncthreads();

    float4 ac[8];
    #pragma unroll
    for (int l = 0; l < 8; ++l) ac[l] = make_float4(0.f, 0.f, 0.f, 0.f);

    const int q0 = g * 32;
    float4 v0 = v4[(size_t)(q0 + 0) * 64 + lane];
    float4 v1 = v4[(size_t)(q0 + 1) * 64 + lane];
    float4 v2 = v4[(size_t)(q0 + 2) * 64 + lane];
    float4 v3 = v4[(size_t)(q0 + 3) * 64 + lane];
    #pragma unroll
    for (int qs = 0; qs < 8; ++qs) {
        const int q = q0 + qs * 4;
        float4 n0, n1, n2, n3;
        if (qs < 7) {                                          // prefetch next step
            n0 = v4[(size_t)(q + 4) * 64 + lane];
            n1 = v4[(size_t)(q + 5) * 64 + lane];
            n2 = v4[(size_t)(q + 6) * 64 + lane];
            n3 = v4[(size_t)(q + 7) * 64 + lane];
        }
        float4 a[8];
        #pragma unroll
        for (int l = 0; l < 8; ++l)
            a[l] = *(const float4*)&s_attn[l][q];              // LDS broadcast
        #pragma unroll
        for (int l = 0; l < 8; ++l) {
            ac[l].x += a[l].x * v0.x; ac[l].y += a[l].x * v0.y;
            ac[l].z += a[l].x * v0.z; ac[l].w += a[l].x * v0.w;
            ac[l].x += a[l].y * v1.x; ac[l].y += a[l].y * v1.y;
            ac[l].z += a[l].y * v1.z; ac[l].w += a[l].y * v1.w;
            ac[l].x += a[l].z * v2.x; ac[l].y += a[l].z * v2.y;
            ac[l].z += a[l].z * v2.z; ac[l].w += a[l].z * v2.w;
            ac[l].x += a[l].w * v3.x; ac[l].y += a[l].w * v3.y;
            ac[l].z += a[l].w * v3.z; ac[l].w += a[l].w * v3.w;
        }
        if (qs < 7) { v0 = n0; v1 = n1; v2 = n2; v3 = n3; }
    }

    // tree reduce over the 16 q-groups: 16 -> 8 -> 4 -> 2 -> 1
    if (g >= 8) {
        #pragma unroll
        for (int l = 0; l < 8; ++l) red[g - 8][l][lane] = ac[l];
    }
    __syncthreads();
    if (g < 8) {
        #pragma unroll
        for (int l = 0; l < 8; ++l) {
            const float4 r = red[g][l][lane];
            ac[l].x += r.x; ac[l].y += r.y; ac[l].z += r.z; ac[l].w += r.w;
        }
    }
    __syncthreads();
    if (g >= 4 && g < 8) {
        #pragma unroll
        for (int l = 0; l < 8; ++l) red[g - 4][l][lane] = ac[l];
    }
    __syncthreads();
    if (g < 4) {
        #pragma unroll
        for (int l = 0; l < 8; ++l) {
            const float4 r = red[g][l][lane];
            ac[l].x += r.x; ac[l].y += r.y; ac[l].z += r.z; ac[l].w += r.w;
        }
    }
    __syncthreads();
    if (g == 2 || g == 3) {
        #pragma unroll
        for (int l = 0; l < 8; ++l) red[g - 2][l][lane] = ac[l];
    }
    __syncthreads();
    if (g < 2) {
        #pragma unroll
        for (int l = 0; l < 8; ++l) {
            const float4 r = red[g][l][lane];
            ac[l].x += r.x; ac[l].y += r.y; ac[l].z += r.z; ac[l].w += r.w;
        }
    }
    __syncthreads();
    if (g == 1) {
        #pragma unroll
        for (int l = 0; l < 8; ++l) red[0][l][lane] = ac[l];
    }
    __syncthreads();
    if (g == 0) {
        #pragma unroll
        for (int l = 0; l < 8; ++l) {
            const float4 r = red[0][l][lane];
            ac[l].x += r.x; ac[l].y += r.y; ac[l].z += r.z; ac[l].w += r.w;
            ((float4*)ctx)[(size_t)(row0 + l) * 64 + lane] = ac[l];
        }
    }
}

extern "C" void kernel_launch(void* const* d_in, const int* in_sizes, int n_in,
                              void* d_out, int out_size, void* d_ws, size_t ws_size,
                              hipStream_t stream) {
    const float* query = (const float*)d_in[0];
    const float* key   = (const float*)d_in[1];
    const float* value = (const float*)d_in[2];
    const float* Wc1   = (const float*)d_in[3];
    const float* Wc2   = (const float*)d_in[4];
    const float* vc    = (const float*)d_in[5];

    float* ctx  = (float*)d_out;                          // [B, Lk, D]
    float* attn = (float*)d_out + (size_t)NB * LK * DD;   // [B, Lk, Lq]

    // Scratch aliases ctx region; safe ONLY because of kernel boundaries
    // (K2 fully drains before K3 overwrites). Fusing K2+K3 is impossible:
    // live-peak attn(4MB)+ctx(2MB)+EqT/Ek(2MB) > 6MB out buffer, d_ws races
    // (prior session), grid barriers falsified (R3: 240us). 3 dispatches is
    // structurally forced.
    float* EqT = ctx;                                     // [B, E, Lq]
    float* Ek  = ctx + (size_t)NB * LQ * EE;              // [B, Lk, E]

    proj_exp_kernel<<<dim3(1024), dim3(256), 0, stream>>>(query, key, Wc1, Wc2, EqT, Ek);
    atten_kernel<<<dim3(NB * (LK / 4)), dim3(512), 0, stream>>>(EqT, Ek, vc, attn);
    context_kernel<<<dim3(NB * (LK / 8)), dim3(1024), 0, stream>>>(attn, value, ctx);
}